// Round 1
// 315.223 us; speedup vs baseline: 1.0012x; 1.0012x over previous
//
#include <hip/hip_runtime.h>
#include <math.h>

#define BATCH 8
#define CH    256
#define HWPIX 4096
#define CQK_  32

typedef __bf16 bf16x8 __attribute__((ext_vector_type(8)));
typedef __bf16 bf16x4 __attribute__((ext_vector_type(4)));
typedef __bf16 bf16x2 __attribute__((ext_vector_type(2)));
typedef float  f32x4  __attribute__((ext_vector_type(4)));

#define FS_STR 68   // LDS transpose-tile row stride in bf16 (136 B: 8B-aligned)

// load a bf16x8 fragment from LDS as two 8B halves (rows only 8B-aligned)
static __device__ inline bf16x8 ld_frag(const __bf16* p) {
  bf16x4 lo = *(const bf16x4*)p;
  bf16x4 hi = *(const bf16x4*)(p + 4);
  return __builtin_shufflevector(lo, hi, 0, 1, 2, 3, 4, 5, 6, 7);
}

// load 8 consecutive fp32 from a W row, convert to bf16x8 fragment
static __device__ inline bf16x8 w_frag(const float* p) {
  const float4 a = *(const float4*)p;
  const float4 b = *(const float4*)(p + 4);
  bf16x8 r;
  r[0] = (__bf16)a.x; r[1] = (__bf16)a.y; r[2] = (__bf16)a.z; r[3] = (__bf16)a.w;
  r[4] = (__bf16)b.x; r[5] = (__bf16)b.y; r[6] = (__bf16)b.z; r[7] = (__bf16)b.w;
  return r;
}

// ---- Fused projections. grid (64 n-tiles, 3 modes, 8 b), block 256 = 4 waves.
// mode 0: Q -> qT[b][n][32] AND K -> kT[b][n][32] (both staged)
// mode 1,2: V c-half (mode-1)*128 -> vv[b][c][hw]
__global__ __launch_bounds__(256, 4) void proj_all(
    const float* __restrict__ f1, const float* __restrict__ f2,
    const float* __restrict__ f3,
    const float* __restrict__ wq, const float* __restrict__ bq,
    const float* __restrict__ wk, const float* __restrict__ bk,
    const float* __restrict__ wv, const float* __restrict__ bv,
    __bf16* __restrict__ qT, __bf16* __restrict__ kT, __bf16* __restrict__ vv)
{
  __shared__ __align__(16) __bf16 f_s[2][64 * FS_STR];  // [n][cin] transposed tiles
  const int t    = threadIdx.x;
  const int w    = __builtin_amdgcn_readfirstlane(t >> 6);
  const int lane = t & 63;
  const int q16  = lane & 15;
  const int quad = lane >> 4;
  const int b    = blockIdx.z;
  const int n0   = blockIdx.x * 64;
  const int mode = blockIdx.y;

  // staging helper: f[c0..+64)[n0..+64) -> dst[n][cin] bf16 (transposed)
  const int sn  = (t & 15) * 4;
  const int scp = (t >> 4) * 2;
#define STAGE(fb, c0, dst)                                                      \
  {                                                                             \
    _Pragma("unroll") for (int rr = 0; rr < 2; ++rr) {                          \
      const int c = rr * 32 + scp;                                              \
      const float4 a0 = *(const float4*)&(fb)[(size_t)((c0) + c) * HWPIX + sn]; \
      const float4 a1 = *(const float4*)&(fb)[(size_t)((c0) + c + 1) * HWPIX + sn]; \
      _Pragma("unroll") for (int i = 0; i < 4; ++i) {                           \
        bf16x2 pk;                                                              \
        pk[0] = (__bf16)((const float*)&a0)[i];                                 \
        pk[1] = (__bf16)((const float*)&a1)[i];                                 \
        *(bf16x2*)&(dst)[(sn + i) * FS_STR + c] = pk;                           \
      }                                                                         \
    }                                                                           \
  }

  if (mode == 0) {
    const float* f1b = f1 + (size_t)b * CH * HWPIX + n0;
    const float* f2b = f2 + (size_t)b * CH * HWPIX + n0;
    f32x4 accQ[2], accK[2];
#pragma unroll
    for (int i = 0; i < 2; ++i) {
      accQ[i] = (f32x4){0.f, 0.f, 0.f, 0.f};
      accK[i] = (f32x4){0.f, 0.f, 0.f, 0.f};
    }
    for (int c0 = 0; c0 < CH; c0 += 64) {
      STAGE(f1b, c0, f_s[0]);
      STAGE(f2b, c0, f_s[1]);
      __syncthreads();
      bf16x8 afQ[2], afK[2];
#pragma unroll
      for (int kh = 0; kh < 2; ++kh) {
        afQ[kh] = ld_frag(&f_s[0][(16 * w + q16) * FS_STR + 32 * kh + quad * 8]);
        afK[kh] = ld_frag(&f_s[1][(16 * w + q16) * FS_STR + 32 * kh + quad * 8]);
      }
#pragma unroll
      for (int ot = 0; ot < 2; ++ot) {
#pragma unroll
        for (int kh = 0; kh < 2; ++kh) {
          const bf16x8 wfq =
              w_frag(wq + (size_t)(16 * ot + q16) * CH + c0 + 32 * kh + quad * 8);
          accQ[ot] = __builtin_amdgcn_mfma_f32_16x16x32_bf16(afQ[kh], wfq, accQ[ot], 0, 0, 0);
          const bf16x8 wfk =
              w_frag(wk + (size_t)(16 * ot + q16) * CH + c0 + 32 * kh + quad * 8);
          accK[ot] = __builtin_amdgcn_mfma_f32_16x16x32_bf16(afK[kh], wfk, accK[ot], 0, 0, 0);
        }
      }
      __syncthreads();
    }
    const float bq0 = bq[q16], bq1 = bq[16 + q16];
    const float bk0 = bk[q16], bk1 = bk[16 + q16];
#pragma unroll
    for (int r = 0; r < 4; ++r) {
      const size_t row = (size_t)b * HWPIX + n0 + 16 * w + quad * 4 + r;
      qT[row * CQK_ + q16]      = (__bf16)(accQ[0][r] + bq0);
      qT[row * CQK_ + 16 + q16] = (__bf16)(accQ[1][r] + bq1);
      kT[row * CQK_ + q16]      = (__bf16)(accK[0][r] + bk0);
      kT[row * CQK_ + 16 + q16] = (__bf16)(accK[1][r] + bk1);
    }
  } else {
    const int cbase = (mode - 1) * 128;
    const float* f3b = f3 + (size_t)b * CH * HWPIX + n0;
    f32x4 acc[2][4];
#pragma unroll
    for (int ct = 0; ct < 2; ++ct)
#pragma unroll
      for (int nt = 0; nt < 4; ++nt) acc[ct][nt] = (f32x4){0.f, 0.f, 0.f, 0.f};

    for (int c0 = 0; c0 < CH; c0 += 64) {
      STAGE(f3b, c0, f_s[0]);
      __syncthreads();
      bf16x8 af[2][2];  // [ct][kh] : W rows (c)
#pragma unroll
      for (int ct = 0; ct < 2; ++ct)
#pragma unroll
        for (int kh = 0; kh < 2; ++kh)
          af[ct][kh] = w_frag(wv + (size_t)(cbase + 64 * ct + 16 * w + q16) * CH
                              + c0 + 32 * kh + quad * 8);
#pragma unroll
      for (int nt = 0; nt < 4; ++nt) {
#pragma unroll
        for (int kh = 0; kh < 2; ++kh) {
          const bf16x8 bfr = ld_frag(&f_s[0][(16 * nt + q16) * FS_STR + 32 * kh + quad * 8]);
#pragma unroll
          for (int ct = 0; ct < 2; ++ct)
            acc[ct][nt] = __builtin_amdgcn_mfma_f32_16x16x32_bf16(
                af[ct][kh], bfr, acc[ct][nt], 0, 0, 0);
        }
      }
      __syncthreads();
    }
#pragma unroll
    for (int ct = 0; ct < 2; ++ct) {
      const float4 bi = *(const float4*)&bv[cbase + 64 * ct + 16 * w + quad * 4];
#pragma unroll
      for (int nt = 0; nt < 4; ++nt) {
#pragma unroll
        for (int r = 0; r < 4; ++r) {
          const int c = cbase + 64 * ct + 16 * w + quad * 4 + r;
          vv[((size_t)b * CH + c) * HWPIX + n0 + 16 * nt + q16] =
              (__bf16)(acc[ct][nt][r] + ((const float*)&bi)[r]);
        }
      }
    }
  }
#undef STAGE
}

// ---- Pipelined flash attention, 8 waves/block (512 thr) for 16 waves/CU.
// grid 512: b = bx&7 (XCD-pinned), q-tile = bx>>3 (64 q).
// Scores: wave w owns q rows [16*(w&3), +16) x m half (w>>2)*32 of each 64-key tile.
//   Computed SWAPPED (mfma(K,Q)) so each lane holds 4 consecutive keys -> b64 P writes,
//   and the softmax row-sum is lane-local (row = q16).
// AV: wave w owns output channels [32w, 32w+64... +32).
// P tile: [64 q][64 m] bf16, row stride exactly 128 B, byte ^= ((q&7)<<4) XOR swizzle
//   (conflict-free-ish for both the b64 writes and the 16-row b128 reads).
__global__ __launch_bounds__(512, 4) void attn_kernel(
    const __bf16* __restrict__ qT, const __bf16* __restrict__ kT,
    const __bf16* __restrict__ vv, float* __restrict__ out)
{
  __shared__ __align__(16) __bf16 p_s[2][64 * 64];  // [q][m], stride 64 bf16 = 128 B
  __shared__ float L_s[2][64];

  const int t    = threadIdx.x;
  const int w    = __builtin_amdgcn_readfirstlane(t >> 6);
  const int lane = t & 63;
  const int q16  = lane & 15;
  const int quad = lane >> 4;
  const int qb   = w & 3;   // score q-block (16 rows)
  const int hb   = w >> 2;  // score m-half (32 of 64 keys)
  const int swz  = (q16 & 7) << 4;

  const int b  = blockIdx.x & 7;
  const int q0 = (blockIdx.x >> 3) * 64;

  const __bf16* kTb = kT + (size_t)b * HWPIX * CQK_;
  // lane offset within a 64-key K tile: key = 32*hb + 16*mt + q16, ck = quad*8..+8
  const size_t koff = (size_t)(32 * hb + q16) * CQK_ + quad * 8;

  // running V pointers (advance 64 keys = 128 B per iter); ch = 32w + 16ct + q16
  const __bf16* vp[2];
#pragma unroll
  for (int ct = 0; ct < 2; ++ct)
    vp[ct] = vv + ((size_t)b * CH + 32 * w + 16 * ct + q16) * HWPIX + quad * 8;

  // Q fragment: q row = q0 + 16*qb + q16 (used as B-operand in swapped scores)
  const bf16x8 qfrag =
      *(const bf16x8*)(qT + ((size_t)b * HWPIX + q0 + 16 * qb + q16) * CQK_ + quad * 8);

  f32x4 oacc[2][4];
#pragma unroll
  for (int i = 0; i < 2; ++i)
#pragma unroll
    for (int j = 0; j < 4; ++j)
      oacc[i][j] = (f32x4){0.f, 0.f, 0.f, 0.f};
  float Lp = 0.f;  // lane-local: partial row-sum of exp for q row 16qb+q16, m-half hb

  // ---- prologue: scores tile 0 -> p_s[0]; kf <- tile 1
  bf16x8 kf[2];
#pragma unroll
  for (int mt = 0; mt < 2; ++mt)
    kf[mt] = *(const bf16x8*)(kTb + koff + mt * 512);
  {
    f32x4 Sv[2];
#pragma unroll
    for (int mt = 0; mt < 2; ++mt)
      Sv[mt] = __builtin_amdgcn_mfma_f32_16x16x32_bf16(
          kf[mt], qfrag, (f32x4){0.f, 0.f, 0.f, 0.f}, 0, 0, 0);
    const __bf16* kb1 = kTb + 64 * CQK_;
#pragma unroll
    for (int mt = 0; mt < 2; ++mt)
      kf[mt] = *(const bf16x8*)(kb1 + koff + mt * 512);
    char* pw = (char*)p_s[0] + (16 * qb + q16) * 128;
#pragma unroll
    for (int mt = 0; mt < 2; ++mt) {
      bf16x4 pk;
#pragma unroll
      for (int r = 0; r < 4; ++r) {
        const float e = __expf(Sv[mt][r]);  // key = 32hb + 16mt + 4quad + r
        Lp += e;
        pk[r] = (__bf16)e;
      }
      *(bf16x4*)(pw + ((64 * hb + 32 * mt + 8 * quad) ^ swz)) = pk;
    }
  }
  __syncthreads();

  // ---- main loop: iter i does AV for tile i, scores+exp for tile i+1
  for (int i = 0; i < 64; ++i) {
    // V fragments for tile i (issued first; consumed after score/exp phase)
    bf16x8 vf[2][2];
#pragma unroll
    for (int ct = 0; ct < 2; ++ct)
#pragma unroll
      for (int mh = 0; mh < 2; ++mh)
        vf[ct][mh] = *(const bf16x8*)(vp[ct] + mh * 32);

    // P fragments for tile i (swizzled reads; all 64 q rows)
    const char* pb = (const char*)p_s[i & 1];
    bf16x8 pf[4][2];
#pragma unroll
    for (int nt = 0; nt < 4; ++nt)
#pragma unroll
      for (int mh = 0; mh < 2; ++mh)
        pf[nt][mh] = *(const bf16x8*)(pb + (16 * nt + q16) * 128
                                      + ((64 * mh + 16 * quad) ^ swz));

    if (i < 63) {
      // scores for tile i+1 (kf prefetched last iter), swapped operands
      f32x4 Sv[2];
#pragma unroll
      for (int mt = 0; mt < 2; ++mt)
        Sv[mt] = __builtin_amdgcn_mfma_f32_16x16x32_bf16(
            kf[mt], qfrag, (f32x4){0.f, 0.f, 0.f, 0.f}, 0, 0, 0);
      // prefetch kf for tile i+2
      const __bf16* kb2 = kTb + (size_t)((i + 2) & 63) * (64 * CQK_);
#pragma unroll
      for (int mt = 0; mt < 2; ++mt)
        kf[mt] = *(const bf16x8*)(kb2 + koff + mt * 512);
      // exp + packed b64 write of P[i+1] into the other buffer
      char* pw = (char*)p_s[(i + 1) & 1] + (16 * qb + q16) * 128;
#pragma unroll
      for (int mt = 0; mt < 2; ++mt) {
        bf16x4 pk;
#pragma unroll
        for (int r = 0; r < 4; ++r) {
          const float e = __expf(Sv[mt][r]);
          Lp += e;
          pk[r] = (__bf16)e;
        }
        *(bf16x4*)(pw + ((64 * hb + 32 * mt + 8 * quad) ^ swz)) = pk;
      }
    }

    // AV for tile i: O[ch = 32w+16ct+...][q = 16nt+...] += V * P
#pragma unroll
    for (int ct = 0; ct < 2; ++ct)
#pragma unroll
      for (int nt = 0; nt < 4; ++nt)
#pragma unroll
        for (int mh = 0; mh < 2; ++mh)
          oacc[ct][nt] = __builtin_amdgcn_mfma_f32_16x16x32_bf16(
              vf[ct][mh], pf[nt][mh], oacc[ct][nt], 0, 0, 0);

#pragma unroll
    for (int ct = 0; ct < 2; ++ct) vp[ct] += 64;
    __syncthreads();
  }

  // ---- finalize L: lane-local partial -> sum over the 4 quads (same q16)
  Lp += __shfl_xor(Lp, 16);
  Lp += __shfl_xor(Lp, 32);
  if (quad == 0) L_s[hb][16 * qb + q16] = Lp;
  __syncthreads();

  float rinv[4];
#pragma unroll
  for (int nt = 0; nt < 4; ++nt)
    rinv[nt] = 1.0f / (L_s[0][16 * nt + q16] + L_s[1][16 * nt + q16]);

  float* ob = out + ((size_t)b * CH + 32 * w) * HWPIX + q0;
#pragma unroll
  for (int ct = 0; ct < 2; ++ct)
#pragma unroll
    for (int r = 0; r < 4; ++r)
#pragma unroll
      for (int nt = 0; nt < 4; ++nt)
        ob[(size_t)(16 * ct + quad * 4 + r) * HWPIX + 16 * nt + q16] =
            oacc[ct][nt][r] * rinv[nt];
}

extern "C" void kernel_launch(void* const* d_in, const int* in_sizes, int n_in,
                              void* d_out, int out_size, void* d_ws, size_t ws_size,
                              hipStream_t stream)
{
  const float* f1 = (const float*)d_in[0];
  const float* f2 = (const float*)d_in[1];
  const float* f3 = (const float*)d_in[2];
  const float* wq = (const float*)d_in[3];
  const float* bq = (const float*)d_in[4];
  const float* wk = (const float*)d_in[5];
  const float* bk = (const float*)d_in[6];
  const float* wv = (const float*)d_in[7];
  const float* bv = (const float*)d_in[8];
  float* outp = (float*)d_out;

  // workspace: qT [8][4096][32] | kT [8][4096][32] | v [8][256][4096]  (bf16, 20 MB)
  __bf16* qTw = (__bf16*)d_ws;
  __bf16* kTw = qTw + (size_t)BATCH * HWPIX * CQK_;
  __bf16* vw  = kTw + (size_t)BATCH * HWPIX * CQK_;

  proj_all<<<dim3(64, 3, 8), 256, 0, stream>>>(f1, f2, f3, wq, bq, wk, bk, wv, bv,
                                               qTw, kTw, vw);
  attn_kernel<<<dim3(512), 512, 0, stream>>>(qTw, kTw, vw, outp);
}